// Round 17
// baseline (272.348 us; speedup 1.0000x reference)
//
#include <hip/hip_runtime.h>
#include <hip/hip_bf16.h>
#include <math.h>

// out = LN2( gelu_erf( LN1(x) @ W^T + bW ) )
// x: [4,4096,2048] f32 -> M=16384 rows. W: [2048,2048] f32, C[m,e]=sum_d h[m,d]*W[e,d].
// R17: R4-proven K-loop scaled to 128x128 tile / 4 waves / 64KB LDS -> TWO blocks/CU
// (R11's occupancy test redone without the register spill: launch_bounds(256,2), acc=64
// VGPR). Same counted-vmcnt ledger (4 DMA/phase, vmcnt(4)), same LDS line/slot swizzle.
// ln1+Wcvt fused; GEMM epilogue writes bf16 h2; LN2 reads bf16 -> f32 out.

#define D 2048
#define MROWS 16384
#define BMT 128
#define BNT 128
#define KTILES (D / 64)  // 32

typedef __bf16 bf16x8 __attribute__((ext_vector_type(8)));
typedef float f32x4 __attribute__((ext_vector_type(4)));

#define GLP(p) ((const __attribute__((address_space(1))) void*)(p))
#define LDSP(p) ((__attribute__((address_space(3))) void*)(p))
#define S_VMCNT(n) asm volatile("s_waitcnt vmcnt(" #n ")" ::: "memory")
#define MEMFENCE() asm volatile("" ::: "memory")
#define BAR() __builtin_amdgcn_s_barrier()
#define SCHED_FENCE() __builtin_amdgcn_sched_barrier(0)

__device__ __forceinline__ float gelu_f(float v) {
  return 0.5f * v * (1.0f + erff(v * 0.70710678118654752f));
}

// ---------------- LN1 (rows 0..MROWS-1) + W cvt (tail blocks), fused ----------------
__global__ __launch_bounds__(256) void ln1f_kernel(
    const float* __restrict__ x, const float* __restrict__ g,
    const float* __restrict__ b, __hip_bfloat16* __restrict__ outA,
    const float* __restrict__ W, __hip_bfloat16* __restrict__ Wb) {
  const int tid = threadIdx.x;
  const int bid = blockIdx.x;
  if (bid >= MROWS) {
    const int i = (bid - MROWS) * 256 + tid;          // 0 .. D*D/8-1
    const float4* p = (const float4*)W + 2 * (size_t)i;
    float4 a = p[0], c = p[1];
    alignas(16) __hip_bfloat16 h[8] = {
        __float2bfloat16(a.x), __float2bfloat16(a.y),
        __float2bfloat16(a.z), __float2bfloat16(a.w),
        __float2bfloat16(c.x), __float2bfloat16(c.y),
        __float2bfloat16(c.z), __float2bfloat16(c.w)};
    *(uint4*)(Wb + (size_t)i * 8) = *(const uint4*)h;
    return;
  }
  const size_t row = bid;
  const float4* xr = (const float4*)(x + row * D);
  float4 v0 = xr[2 * tid];
  float4 v1 = xr[2 * tid + 1];
  float s  = v0.x + v0.y + v0.z + v0.w + v1.x + v1.y + v1.z + v1.w;
  float ss = v0.x*v0.x + v0.y*v0.y + v0.z*v0.z + v0.w*v0.w
           + v1.x*v1.x + v1.y*v1.y + v1.z*v1.z + v1.w*v1.w;
#pragma unroll
  for (int off = 32; off > 0; off >>= 1) {
    s  += __shfl_down(s, off, 64);
    ss += __shfl_down(ss, off, 64);
  }
  __shared__ float red[8];
  const int w = tid >> 6;
  if ((tid & 63) == 0) { red[w] = s; red[w + 4] = ss; }
  __syncthreads();
  s  = red[0] + red[1] + red[2] + red[3];
  ss = red[4] + red[5] + red[6] + red[7];
  const float mu  = s * (1.0f / D);
  const float var = ss * (1.0f / D) - mu * mu;
  const float inv = rsqrtf(var + 1e-5f);
  const float4* gv = (const float4*)g;
  const float4* bv = (const float4*)b;
  float4 g0 = gv[2 * tid], g1 = gv[2 * tid + 1];
  float4 b0 = bv[2 * tid], b1 = bv[2 * tid + 1];
  alignas(16) __hip_bfloat16 h[8];
  h[0] = __float2bfloat16((v0.x - mu) * inv * g0.x + b0.x);
  h[1] = __float2bfloat16((v0.y - mu) * inv * g0.y + b0.y);
  h[2] = __float2bfloat16((v0.z - mu) * inv * g0.z + b0.z);
  h[3] = __float2bfloat16((v0.w - mu) * inv * g0.w + b0.w);
  h[4] = __float2bfloat16((v1.x - mu) * inv * g1.x + b1.x);
  h[5] = __float2bfloat16((v1.y - mu) * inv * g1.y + b1.y);
  h[6] = __float2bfloat16((v1.z - mu) * inv * g1.z + b1.z);
  h[7] = __float2bfloat16((v1.w - mu) * inv * g1.w + b1.w);
  *(uint4*)(outA + row * D + (size_t)tid * 8) = *(const uint4*)h;
}

// ---------------- GEMM: 128x128 tile, 4 waves (2M x 2N), 64KB LDS, 2 blocks/CU ----------------
// kh-region per operand: 128 rows x 32 cols bf16 = 64 lines x 128B; line=row>>1,
// slot=(2*lk+(row&1))^((row>>1)&7). DMA dest linear; inverse swizzle on global SOURCE.
template <bool BFO>
__global__ __launch_bounds__(256, 2) void gemm_kernel(
    const __hip_bfloat16* __restrict__ A,
    const __hip_bfloat16* __restrict__ Bw,
    const float* __restrict__ bias,
    void* __restrict__ Cout) {
  __shared__ __hip_bfloat16 sA[2 * 2 * 128 * 32];  // 32KB [buf][kh][64 lines][128B]
  __shared__ __hip_bfloat16 sB[2 * 2 * 128 * 32];  // 32KB
  const int tid = threadIdx.x;                     // 0..255
  const int l = tid & 63;
  const int wid = tid >> 6;                        // 0..3
  const int fr = l & 15;
  const int lk = l >> 4;
  const size_t m0 = (size_t)blockIdx.x * BMT;
  const int n0 = blockIdx.y * BNT;
  const int wm2 = wid >> 1;                        // wave row half (0/1) -> rows wm2*64..
  const int wn2 = wid & 1;                         // wave col half -> cols wn2*64..

  // read offsets: row r = wm2*64 + mi*16 + fr -> line wm2*32 + mi*8 + (fr>>1);
  // slot const per lane: (2*lk+(fr&1)) ^ ((fr>>1)&7)
  const int slot = ((2 * lk + (fr & 1)) ^ ((fr >> 1) & 7)) << 4;
  const int aoff = (wm2 * 32 + (fr >> 1)) * 128 + slot;
  const int boff = (wn2 * 32 + (fr >> 1)) * 128 + slot;

  // staging: dest byte tid*16 (lines 0..31 = rows 0..63) and +4096 (rows 64..127)
  const int line = tid >> 3;                       // 0..31
  const int v = (tid & 7) ^ (line & 7);
  const int srow0 = 2 * line + (v & 1);            // 0..63
  const int srow1 = srow0 + 64;
  const int scol = (v >> 1) * 8;
  const int ldd0 = tid * 16;
  const int ldd1 = ldd0 + 4096;
  const __hip_bfloat16* const Ag = A + m0 * D;
  const __hip_bfloat16* const Bg = Bw + (size_t)n0 * D;

  auto stg = [&](const __hip_bfloat16* G, char* lds, int so, int kh, int kt) {
    const __hip_bfloat16* s0 = G + (size_t)srow0 * D + kt * 64 + kh * 32 + scol;
    const __hip_bfloat16* s1 = G + (size_t)srow1 * D + kt * 64 + kh * 32 + scol;
    char* q = lds + (so << 14) + (kh << 13);       // buf stride 16KB, kh stride 8KB
    __builtin_amdgcn_global_load_lds(GLP(s0), LDSP(q + ldd0), 16, 0, 0);
    __builtin_amdgcn_global_load_lds(GLP(s1), LDSP(q + ldd1), 16, 0, 0);
  };

  bf16x8 a[4], b[4];
  f32x4 acc[4][4] = {};

  auto rd = [&](int bo, int kh) {                  // 8 ds_read_b128
    const char* pa = (const char*)sA + bo + (kh << 13) + aoff;
    const char* pb = (const char*)sB + bo + (kh << 13) + boff;
#pragma unroll
    for (int mi = 0; mi < 4; ++mi) a[mi] = *(const bf16x8*)(pa + mi * 1024);
#pragma unroll
    for (int ni = 0; ni < 4; ++ni) b[ni] = *(const bf16x8*)(pb + ni * 1024);
  };
  auto mma = [&]() {                               // 16 MFMA
    __builtin_amdgcn_s_setprio(1);
#pragma unroll
    for (int mi = 0; mi < 4; ++mi)
#pragma unroll
      for (int ni = 0; ni < 4; ++ni)
        acc[mi][ni] = __builtin_amdgcn_mfma_f32_16x16x32_bf16(a[mi], b[ni], acc[mi][ni], 0, 0, 0);
    __builtin_amdgcn_s_setprio(0);
  };

  // prologue: tile 0 into buf0; order Akh0,Bkh0,Akh1,Bkh1 (8 loads in flight)
  MEMFENCE();
  stg(Ag, (char*)sA, 0, 0, 0); stg(Bg, (char*)sB, 0, 0, 0);
  stg(Ag, (char*)sA, 0, 1, 0); stg(Bg, (char*)sB, 0, 1, 0);
  MEMFENCE();

  for (int kt = 0; kt < KTILES - 1; ++kt) {
    const int bo = (kt & 1) << 14;
    const int so = (kt & 1) ^ 1;
    S_VMCNT(4);
    BAR(); MEMFENCE(); SCHED_FENCE();
    rd(bo, 0);
    stg(Ag, (char*)sA, so, 0, kt + 1); stg(Bg, (char*)sB, so, 0, kt + 1);
    MEMFENCE();
    mma();
    S_VMCNT(4);
    BAR(); MEMFENCE(); SCHED_FENCE();
    rd(bo, 1);
    stg(Ag, (char*)sA, so, 1, kt + 1); stg(Bg, (char*)sB, so, 1, kt + 1);
    MEMFENCE();
    mma();
  }
  {
    const int bo = ((KTILES - 1) & 1) << 14;
    S_VMCNT(4);
    BAR(); MEMFENCE(); SCHED_FENCE();
    rd(bo, 0);
    mma();
    S_VMCNT(0);
    BAR(); MEMFENCE(); SCHED_FENCE();
    rd(bo, 1);
    mma();
  }

  // epilogue: bias + gelu (C/D: col=lane&15, row=(lane>>4)*4+reg)
  float bv[4];
#pragma unroll
  for (int ni = 0; ni < 4; ++ni) bv[ni] = bias[n0 + wn2 * 64 + ni * 16 + fr];
#pragma unroll
  for (int mi = 0; mi < 4; ++mi) {
    const size_t rbase = m0 + wm2 * 64 + mi * 16 + lk * 4;
#pragma unroll
    for (int rr = 0; rr < 4; ++rr) {
      const size_t ro = (rbase + rr) * D + n0 + wn2 * 64 + fr;
#pragma unroll
      for (int ni = 0; ni < 4; ++ni) {
        const float val = gelu_f(acc[mi][ni][rr] + bv[ni]);
        if constexpr (BFO)
          ((__hip_bfloat16*)Cout)[ro + ni * 16] = __float2bfloat16(val);
        else
          ((float*)Cout)[ro + ni * 16] = val;
      }
    }
  }
}

// ---------------- LN2 (f32 in-place fallback) ----------------
__global__ __launch_bounds__(256) void ln2_kernel(
    float* __restrict__ C, const float* __restrict__ g, const float* __restrict__ b) {
  const int tid = threadIdx.x;
  const size_t row = blockIdx.x;
  float4* cr = (float4*)(C + row * D);
  float4 v0 = cr[2 * tid], v1 = cr[2 * tid + 1];
  float s  = v0.x + v0.y + v0.z + v0.w + v1.x + v1.y + v1.z + v1.w;
  float ss = v0.x*v0.x + v0.y*v0.y + v0.z*v0.z + v0.w*v0.w
           + v1.x*v1.x + v1.y*v1.y + v1.z*v1.z + v1.w*v1.w;
#pragma unroll
  for (int off = 32; off > 0; off >>= 1) {
    s  += __shfl_down(s, off, 64);
    ss += __shfl_down(ss, off, 64);
  }
  __shared__ float red[8];
  const int w = tid >> 6;
  if ((tid & 63) == 0) { red[w] = s; red[w + 4] = ss; }
  __syncthreads();
  s  = red[0] + red[1] + red[2] + red[3];
  ss = red[4] + red[5] + red[6] + red[7];
  const float mu  = s * (1.0f / D);
  const float var = ss * (1.0f / D) - mu * mu;
  const float inv = rsqrtf(var + 1e-5f);
  const float4* gv = (const float4*)g;
  const float4* bv = (const float4*)b;
  float4 g0 = gv[2 * tid], g1 = gv[2 * tid + 1];
  float4 b0 = bv[2 * tid], b1 = bv[2 * tid + 1];
  float4 o0, o1;
  o0.x = (v0.x - mu) * inv * g0.x + b0.x;
  o0.y = (v0.y - mu) * inv * g0.y + b0.y;
  o0.z = (v0.z - mu) * inv * g0.z + b0.z;
  o0.w = (v0.w - mu) * inv * g0.w + b0.w;
  o1.x = (v1.x - mu) * inv * g1.x + b1.x;
  o1.y = (v1.y - mu) * inv * g1.y + b1.y;
  o1.z = (v1.z - mu) * inv * g1.z + b1.z;
  o1.w = (v1.w - mu) * inv * g1.w + b1.w;
  cr[2 * tid] = o0;
  cr[2 * tid + 1] = o1;
}

// ---------------- LN2 from bf16 h2 -> f32 out ----------------
__global__ __launch_bounds__(256) void ln2b_kernel(
    const __hip_bfloat16* __restrict__ H, const float* __restrict__ g,
    const float* __restrict__ b, float* __restrict__ out) {
  const int tid = threadIdx.x;
  const size_t row = blockIdx.x;
  const uint4 hv = ((const uint4*)(H + row * D))[tid];   // 8 bf16
  float v[8];
  const unsigned wds[4] = {hv.x, hv.y, hv.z, hv.w};
#pragma unroll
  for (int i = 0; i < 4; ++i) {
    unsigned lo = (wds[i] & 0xffffu) << 16;
    unsigned hi = wds[i] & 0xffff0000u;
    v[2 * i]     = __builtin_bit_cast(float, lo);
    v[2 * i + 1] = __builtin_bit_cast(float, hi);
  }
  float s = 0.f, ss = 0.f;
#pragma unroll
  for (int i = 0; i < 8; ++i) { s += v[i]; ss += v[i] * v[i]; }
#pragma unroll
  for (int off = 32; off > 0; off >>= 1) {
    s  += __shfl_down(s, off, 64);
    ss += __shfl_down(ss, off, 64);
  }
  __shared__ float red[8];
  const int w = tid >> 6;
  if ((tid & 63) == 0) { red[w] = s; red[w + 4] = ss; }
  __syncthreads();
  s  = red[0] + red[1] + red[2] + red[3];
  ss = red[4] + red[5] + red[6] + red[7];
  const float mu  = s * (1.0f / D);
  const float var = ss * (1.0f / D) - mu * mu;
  const float inv = rsqrtf(var + 1e-5f);
  const float4* gv = (const float4*)g;
  const float4* bv = (const float4*)b;
  float4 g0 = gv[2 * tid], g1 = gv[2 * tid + 1];
  float4 b0 = bv[2 * tid], b1 = bv[2 * tid + 1];
  float4 o0, o1;
  o0.x = (v[0] - mu) * inv * g0.x + b0.x;
  o0.y = (v[1] - mu) * inv * g0.y + b0.y;
  o0.z = (v[2] - mu) * inv * g0.z + b0.z;
  o0.w = (v[3] - mu) * inv * g0.w + b0.w;
  o1.x = (v[4] - mu) * inv * g1.x + b1.x;
  o1.y = (v[5] - mu) * inv * g1.y + b1.y;
  o1.z = (v[6] - mu) * inv * g1.z + b1.z;
  o1.w = (v[7] - mu) * inv * g1.w + b1.w;
  float4* orow = (float4*)(out + row * D);
  orow[2 * tid] = o0;
  orow[2 * tid + 1] = o1;
}

extern "C" void kernel_launch(void* const* d_in, const int* in_sizes, int n_in,
                              void* d_out, int out_size, void* d_ws, size_t ws_size,
                              hipStream_t stream) {
  const float* x  = (const float*)d_in[0];
  const float* W  = (const float*)d_in[1];
  const float* bW = (const float*)d_in[2];
  const float* g1 = (const float*)d_in[3];
  const float* b1 = (const float*)d_in[4];
  const float* g2 = (const float*)d_in[5];
  const float* b2 = (const float*)d_in[6];
  float* out = (float*)d_out;

  __hip_bfloat16* Abf = (__hip_bfloat16*)d_ws;                    // 67MB
  __hip_bfloat16* Wbf = Abf + (size_t)MROWS * D;                  // +8.4MB
  __hip_bfloat16* H2  = Wbf + (size_t)D * D;                      // +67MB (optional)
  const size_t need = ((size_t)MROWS * D * 2 + (size_t)D * D) * sizeof(__hip_bfloat16);

  ln1f_kernel<<<MROWS + (D * D / 8) / 256, 256, 0, stream>>>(x, g1, b1, Abf, W, Wbf);
  dim3 grid(MROWS / BMT, D / BNT);
  if (ws_size >= need) {
    gemm_kernel<true><<<grid, 256, 0, stream>>>(Abf, Wbf, bW, (void*)H2);
    ln2b_kernel<<<MROWS, 256, 0, stream>>>(H2, g2, b2, out);
  } else {
    gemm_kernel<false><<<grid, 256, 0, stream>>>(Abf, Wbf, bW, (void*)out);
    ln2_kernel<<<MROWS, 256, 0, stream>>>(out, g2, b2);
  }
}

// Round 18
// 228.720 us; speedup vs baseline: 1.1907x; 1.1907x over previous
//
#include <hip/hip_runtime.h>
#include <hip/hip_bf16.h>
#include <math.h>

// out = LN2( gelu_erf( LN1(x) @ W^T + bW ) )
// x: [4,4096,2048] f32 -> M=16384 rows. W: [2048,2048] f32, C[m,e]=sum_d h[m,d]*W[e,d].
// R18 (final): revert to R10, the session's best measured config (229.9 us total).
// GEMM = R4 2-phase 256x256 double-buffer (160 us / 845 TF), bf16-h2 epilogue, ln2b.
// Ledger: 9 GEMM structures tested; all alternatives 6-44 us slower than this one.

#define D 2048
#define MROWS 16384
#define BMT 256
#define BNT 256
#define KTILES (D / 64)  // 32

typedef __bf16 bf16x8 __attribute__((ext_vector_type(8)));
typedef float f32x4 __attribute__((ext_vector_type(4)));

#define GLP(p) ((const __attribute__((address_space(1))) void*)(p))
#define LDSP(p) ((__attribute__((address_space(3))) void*)(p))
#define S_VMCNT(n) asm volatile("s_waitcnt vmcnt(" #n ")" ::: "memory")
#define MEMFENCE() asm volatile("" ::: "memory")
#define BAR() __builtin_amdgcn_s_barrier()
#define SCHED_FENCE() __builtin_amdgcn_sched_barrier(0)

__device__ __forceinline__ float gelu_f(float v) {
  return 0.5f * v * (1.0f + erff(v * 0.70710678118654752f));
}

// ---------------- LN1: f32 row -> bf16 row ----------------
__global__ __launch_bounds__(256) void ln1_kernel(
    const float* __restrict__ x, const float* __restrict__ g,
    const float* __restrict__ b, __hip_bfloat16* __restrict__ out) {
  const int tid = threadIdx.x;
  const size_t row = blockIdx.x;
  const float4* xr = (const float4*)(x + row * D);
  float4 v0 = xr[2 * tid];
  float4 v1 = xr[2 * tid + 1];
  float s  = v0.x + v0.y + v0.z + v0.w + v1.x + v1.y + v1.z + v1.w;
  float ss = v0.x*v0.x + v0.y*v0.y + v0.z*v0.z + v0.w*v0.w
           + v1.x*v1.x + v1.y*v1.y + v1.z*v1.z + v1.w*v1.w;
#pragma unroll
  for (int off = 32; off > 0; off >>= 1) {
    s  += __shfl_down(s, off, 64);
    ss += __shfl_down(ss, off, 64);
  }
  __shared__ float red[8];
  const int w = tid >> 6;
  if ((tid & 63) == 0) { red[w] = s; red[w + 4] = ss; }
  __syncthreads();
  s  = red[0] + red[1] + red[2] + red[3];
  ss = red[4] + red[5] + red[6] + red[7];
  const float mu  = s * (1.0f / D);
  const float var = ss * (1.0f / D) - mu * mu;
  const float inv = rsqrtf(var + 1e-5f);
  const float4* gv = (const float4*)g;
  const float4* bv = (const float4*)b;
  float4 g0 = gv[2 * tid], g1 = gv[2 * tid + 1];
  float4 b0 = bv[2 * tid], b1 = bv[2 * tid + 1];
  alignas(16) __hip_bfloat16 h[8];
  h[0] = __float2bfloat16((v0.x - mu) * inv * g0.x + b0.x);
  h[1] = __float2bfloat16((v0.y - mu) * inv * g0.y + b0.y);
  h[2] = __float2bfloat16((v0.z - mu) * inv * g0.z + b0.z);
  h[3] = __float2bfloat16((v0.w - mu) * inv * g0.w + b0.w);
  h[4] = __float2bfloat16((v1.x - mu) * inv * g1.x + b1.x);
  h[5] = __float2bfloat16((v1.y - mu) * inv * g1.y + b1.y);
  h[6] = __float2bfloat16((v1.z - mu) * inv * g1.z + b1.z);
  h[7] = __float2bfloat16((v1.w - mu) * inv * g1.w + b1.w);
  *(uint4*)(out + row * D + (size_t)tid * 8) = *(const uint4*)h;
}

// ---------------- W: f32 -> bf16 ----------------
__global__ __launch_bounds__(256) void cvt_kernel(
    const float* __restrict__ W, __hip_bfloat16* __restrict__ Wb, int n8) {
  const int i = blockIdx.x * 256 + threadIdx.x;
  if (i >= n8) return;
  const float4* p = (const float4*)W + 2 * (size_t)i;
  float4 a = p[0], c = p[1];
  alignas(16) __hip_bfloat16 h[8] = {
      __float2bfloat16(a.x), __float2bfloat16(a.y),
      __float2bfloat16(a.z), __float2bfloat16(a.w),
      __float2bfloat16(c.x), __float2bfloat16(c.y),
      __float2bfloat16(c.z), __float2bfloat16(c.w)};
  *(uint4*)(Wb + (size_t)i * 8) = *(const uint4*)h;
}

// ---------------- GEMM (R4-identical K-loop, 160us/845TF measured) ----------------
// LDS per operand: [2 buf][2 kh][16KB]; kh-region = 256 rows x 32 cols bf16 as 128 lines x
// 128B; (row, chunk lk) at line=row>>1, slot=(2*lk+(row&1))^((row>>1)&7). DMA dest linear;
// swizzle applied on the global SOURCE.
template <bool BFO>
__global__ __launch_bounds__(512, 2) void gemm_kernel(
    const __hip_bfloat16* __restrict__ A,
    const __hip_bfloat16* __restrict__ Bw,
    const float* __restrict__ bias,
    void* __restrict__ Cout) {
  __shared__ __hip_bfloat16 sA[2 * 2 * 256 * 32];  // 64KB
  __shared__ __hip_bfloat16 sB[2 * 2 * 256 * 32];  // 64KB
  const int tid = threadIdx.x;
  const int l = tid & 63;
  const int wid = tid >> 6;
  const int fr = l & 15;
  const int lk = l >> 4;
  const size_t m0 = (size_t)blockIdx.x * BMT;
  const int n0 = blockIdx.y * BNT;
  const int whm = wid >> 2;
  const int wn = (wid & 3) * 64;

  const int slot = ((2 * lk + (fr & 1)) ^ (fr >> 1)) << 4;
  const int aoff = whm * 8192 + (fr >> 1) * 128 + slot;
  const int boff = wn * 64 + (fr >> 1) * 128 + slot;

  const int line = tid >> 3;
  const int v = (tid & 7) ^ (line & 7);
  const int srow0 = 2 * line + (v & 1);
  const int srow1 = srow0 + 128;
  const int scol = (v >> 1) * 8;
  const int ldd0 = tid * 16;
  const int ldd1 = ldd0 + 8192;
  const __hip_bfloat16* const Ag = A + m0 * D;
  const __hip_bfloat16* const Bg = Bw + (size_t)n0 * D;

  auto stg = [&](const __hip_bfloat16* G, char* lds, int so, int kh, int kt) {
    const __hip_bfloat16* s0 = G + (size_t)srow0 * D + kt * 64 + kh * 32 + scol;
    const __hip_bfloat16* s1 = G + (size_t)srow1 * D + kt * 64 + kh * 32 + scol;
    char* q = lds + (so << 15) + (kh << 14);
    __builtin_amdgcn_global_load_lds(GLP(s0), LDSP(q + ldd0), 16, 0, 0);
    __builtin_amdgcn_global_load_lds(GLP(s1), LDSP(q + ldd1), 16, 0, 0);
  };

  bf16x8 a[8], b[4];
  f32x4 acc[8][4] = {};

  auto rd = [&](int bo, int kh) {
    const char* pa = (const char*)sA + bo + (kh << 14) + aoff;
    const char* pb = (const char*)sB + bo + (kh << 14) + boff;
#pragma unroll
    for (int mi = 0; mi < 8; ++mi) a[mi] = *(const bf16x8*)(pa + mi * 1024);
#pragma unroll
    for (int ni = 0; ni < 4; ++ni) b[ni] = *(const bf16x8*)(pb + ni * 1024);
  };
  auto mma = [&]() {
    __builtin_amdgcn_s_setprio(1);
#pragma unroll
    for (int mi = 0; mi < 8; ++mi)
#pragma unroll
      for (int ni = 0; ni < 4; ++ni)
        acc[mi][ni] = __builtin_amdgcn_mfma_f32_16x16x32_bf16(a[mi], b[ni], acc[mi][ni], 0, 0, 0);
    __builtin_amdgcn_s_setprio(0);
  };

  // prologue: tile 0 into buf0; order Akh0,Bkh0,Akh1,Bkh1 (8 loads in flight)
  stg(Ag, (char*)sA, 0, 0, 0); stg(Bg, (char*)sB, 0, 0, 0);
  stg(Ag, (char*)sA, 0, 1, 0); stg(Bg, (char*)sB, 0, 1, 0);

  for (int kt = 0; kt < KTILES - 1; ++kt) {
    const int bo = (kt & 1) << 15;
    const int so = (kt & 1) ^ 1;
    S_VMCNT(4);
    BAR(); MEMFENCE(); SCHED_FENCE();
    rd(bo, 0);
    stg(Ag, (char*)sA, so, 0, kt + 1); stg(Bg, (char*)sB, so, 0, kt + 1);
    mma();
    S_VMCNT(4);
    BAR(); MEMFENCE(); SCHED_FENCE();
    rd(bo, 1);
    stg(Ag, (char*)sA, so, 1, kt + 1); stg(Bg, (char*)sB, so, 1, kt + 1);
    mma();
  }
  {
    const int bo = ((KTILES - 1) & 1) << 15;
    S_VMCNT(4);
    BAR(); MEMFENCE(); SCHED_FENCE();
    rd(bo, 0);
    mma();
    S_VMCNT(0);
    BAR(); MEMFENCE(); SCHED_FENCE();
    rd(bo, 1);
    mma();
  }

  // epilogue: bias + gelu (C/D: col=lane&15, row=(lane>>4)*4+reg)
  float bv[4];
#pragma unroll
  for (int ni = 0; ni < 4; ++ni) bv[ni] = bias[n0 + wn + ni * 16 + fr];
#pragma unroll
  for (int mi = 0; mi < 8; ++mi) {
    const size_t rbase = m0 + whm * 128 + mi * 16 + lk * 4;
#pragma unroll
    for (int rr = 0; rr < 4; ++rr) {
      const size_t ro = (rbase + rr) * D + n0 + wn + fr;
#pragma unroll
      for (int ni = 0; ni < 4; ++ni) {
        const float val = gelu_f(acc[mi][ni][rr] + bv[ni]);
        if constexpr (BFO)
          ((__hip_bfloat16*)Cout)[ro + ni * 16] = __float2bfloat16(val);
        else
          ((float*)Cout)[ro + ni * 16] = val;
      }
    }
  }
}

// ---------------- LN2 (f32 in-place fallback) ----------------
__global__ __launch_bounds__(256) void ln2_kernel(
    float* __restrict__ C, const float* __restrict__ g, const float* __restrict__ b) {
  const int tid = threadIdx.x;
  const size_t row = blockIdx.x;
  float4* cr = (float4*)(C + row * D);
  float4 v0 = cr[2 * tid], v1 = cr[2 * tid + 1];
  float s  = v0.x + v0.y + v0.z + v0.w + v1.x + v1.y + v1.z + v1.w;
  float ss = v0.x*v0.x + v0.y*v0.y + v0.z*v0.z + v0.w*v0.w
           + v1.x*v1.x + v1.y*v1.y + v1.z*v1.z + v1.w*v1.w;
#pragma unroll
  for (int off = 32; off > 0; off >>= 1) {
    s  += __shfl_down(s, off, 64);
    ss += __shfl_down(ss, off, 64);
  }
  __shared__ float red[8];
  const int w = tid >> 6;
  if ((tid & 63) == 0) { red[w] = s; red[w + 4] = ss; }
  __syncthreads();
  s  = red[0] + red[1] + red[2] + red[3];
  ss = red[4] + red[5] + red[6] + red[7];
  const float mu  = s * (1.0f / D);
  const float var = ss * (1.0f / D) - mu * mu;
  const float inv = rsqrtf(var + 1e-5f);
  const float4* gv = (const float4*)g;
  const float4* bv = (const float4*)b;
  float4 g0 = gv[2 * tid], g1 = gv[2 * tid + 1];
  float4 b0 = bv[2 * tid], b1 = bv[2 * tid + 1];
  float4 o0, o1;
  o0.x = (v0.x - mu) * inv * g0.x + b0.x;
  o0.y = (v0.y - mu) * inv * g0.y + b0.y;
  o0.z = (v0.z - mu) * inv * g0.z + b0.z;
  o0.w = (v0.w - mu) * inv * g0.w + b0.w;
  o1.x = (v1.x - mu) * inv * g1.x + b1.x;
  o1.y = (v1.y - mu) * inv * g1.y + b1.y;
  o1.z = (v1.z - mu) * inv * g1.z + b1.z;
  o1.w = (v1.w - mu) * inv * g1.w + b1.w;
  cr[2 * tid] = o0;
  cr[2 * tid + 1] = o1;
}

// ---------------- LN2 from bf16 h2 -> f32 out ----------------
__global__ __launch_bounds__(256) void ln2b_kernel(
    const __hip_bfloat16* __restrict__ H, const float* __restrict__ g,
    const float* __restrict__ b, float* __restrict__ out) {
  const int tid = threadIdx.x;
  const size_t row = blockIdx.x;
  const uint4 hv = ((const uint4*)(H + row * D))[tid];   // 8 bf16
  float v[8];
  const unsigned wds[4] = {hv.x, hv.y, hv.z, hv.w};
#pragma unroll
  for (int i = 0; i < 4; ++i) {
    unsigned lo = (wds[i] & 0xffffu) << 16;
    unsigned hi = wds[i] & 0xffff0000u;
    v[2 * i]     = __builtin_bit_cast(float, lo);
    v[2 * i + 1] = __builtin_bit_cast(float, hi);
  }
  float s = 0.f, ss = 0.f;
#pragma unroll
  for (int i = 0; i < 8; ++i) { s += v[i]; ss += v[i] * v[i]; }
#pragma unroll
  for (int off = 32; off > 0; off >>= 1) {
    s  += __shfl_down(s, off, 64);
    ss += __shfl_down(ss, off, 64);
  }
  __shared__ float red[8];
  const int w = tid >> 6;
  if ((tid & 63) == 0) { red[w] = s; red[w + 4] = ss; }
  __syncthreads();
  s  = red[0] + red[1] + red[2] + red[3];
  ss = red[4] + red[5] + red[6] + red[7];
  const float mu  = s * (1.0f / D);
  const float var = ss * (1.0f / D) - mu * mu;
  const float inv = rsqrtf(var + 1e-5f);
  const float4* gv = (const float4*)g;
  const float4* bv = (const float4*)b;
  float4 g0 = gv[2 * tid], g1 = gv[2 * tid + 1];
  float4 b0 = bv[2 * tid], b1 = bv[2 * tid + 1];
  float4 o0, o1;
  o0.x = (v[0] - mu) * inv * g0.x + b0.x;
  o0.y = (v[1] - mu) * inv * g0.y + b0.y;
  o0.z = (v[2] - mu) * inv * g0.z + b0.z;
  o0.w = (v[3] - mu) * inv * g0.w + b0.w;
  o1.x = (v[4] - mu) * inv * g1.x + b1.x;
  o1.y = (v[5] - mu) * inv * g1.y + b1.y;
  o1.z = (v[6] - mu) * inv * g1.z + b1.z;
  o1.w = (v[7] - mu) * inv * g1.w + b1.w;
  float4* orow = (float4*)(out + row * D);
  orow[2 * tid] = o0;
  orow[2 * tid + 1] = o1;
}

extern "C" void kernel_launch(void* const* d_in, const int* in_sizes, int n_in,
                              void* d_out, int out_size, void* d_ws, size_t ws_size,
                              hipStream_t stream) {
  const float* x  = (const float*)d_in[0];
  const float* W  = (const float*)d_in[1];
  const float* bW = (const float*)d_in[2];
  const float* g1 = (const float*)d_in[3];
  const float* b1 = (const float*)d_in[4];
  const float* g2 = (const float*)d_in[5];
  const float* b2 = (const float*)d_in[6];
  float* out = (float*)d_out;

  __hip_bfloat16* Abf = (__hip_bfloat16*)d_ws;                    // 67MB
  __hip_bfloat16* Wbf = Abf + (size_t)MROWS * D;                  // +8.4MB
  __hip_bfloat16* H2  = Wbf + (size_t)D * D;                      // +67MB (optional)
  const size_t need = ((size_t)MROWS * D * 2 + (size_t)D * D) * sizeof(__hip_bfloat16);

  ln1_kernel<<<MROWS, 256, 0, stream>>>(x, g1, b1, Abf);
  cvt_kernel<<<(D * D / 8) / 256, 256, 0, stream>>>(W, Wbf, D * D / 8);
  dim3 grid(MROWS / BMT, D / BNT);
  if (ws_size >= need) {
    gemm_kernel<true><<<grid, 512, 0, stream>>>(Abf, Wbf, bW, (void*)H2);
    ln2b_kernel<<<MROWS, 256, 0, stream>>>(H2, g2, b2, out);
  } else {
    gemm_kernel<false><<<grid, 512, 0, stream>>>(Abf, Wbf, bW, (void*)out);
    ln2_kernel<<<MROWS, 256, 0, stream>>>(out, g2, b2);
  }
}